// Round 16
// baseline (4879.421 us; speedup 1.0000x reference)
//
#include <hip/hip_runtime.h>

#define NB 32
#define NPTS 131072
#define KSAMP 2048
#define NPART 8
#define TPB 512
#define NPT 32                    // points per thread
#define PART_PTS (NPTS / NPART)   // 16384
#define BATCH_F (NPTS * 3)        // floats per batch (393216)
#define SOA_BYTES ((size_t)NB * BATCH_F * 4)   // 48 MB

// R16: SoA repack + float4 scan.
//  Pre-kernel transposes x[b][n][xyz] -> X[b][n], Y[b][n], Z[b][n] in d_ws.
//  FPS kernel (proven 256-block cooperative grid, 8 parts/batch) scans 4
//  points per 3 x global_load_dwordx4 with base+immediate addressing:
//  ~11 issue slots/point vs ~26 on the AoS path (R15: VALU-issue-bound,
//  addressing+scalar loads were ~60% of scan issue; 5 rounds proved the RA
//  never register-carries the coords).
//
//  Thread->point mapping (free to choose; key carries true n): wave w lane l
//  group g owns n = S + w*2048 + g*256 + l*4 + i, so lane l reads 16B at
//  byte l*16 of region (w*8+g) -- perfectly coalesced 64x16B = 1KB/inst.
//  Ascending (g,i) scan keeps in-thread first-index tie-break.
//
// Numerics (bit-exact validated R4/R10):
//   d2  = fma(dz,dz, fma(dx,dx, dy*dy)); md2 = fminf(md2, d2)
//   ONE CR sqrt converts the thread winner to the ref sd domain (CR-sqrt
//   monotone => bitwise equal to ref's iterated min(min_d, sqrt)).
//   Packed key (sd_bits<<32)|(131071-n): u64-max == value+first-index.
//
// Sync per step (R6-proven): wave shfl max -> LDS -> wave0 cross-wave max ->
// tagged publish (agent store) -> wave0 spins on 64B row until all 8 tags
// match -> LDS broadcast -> barrier. Tags 1..2047 disambiguate 0xAA poison
// (tag 0x5555) / stale replay data; double-buffered rows kill WAR.
//
// Fallback (ws too small): R10 kernel reading AoS directly (proven 4649us).

#define GRP8(X) X(0)X(1)X(2)X(3)X(4)X(5)X(6)X(7)
#define RPT32(X) X(0)X(1)X(2)X(3)X(4)X(5)X(6)X(7)X(8)X(9)X(10)X(11)X(12) \
  X(13)X(14)X(15)X(16)X(17)X(18)X(19)X(20)X(21)X(22)X(23)X(24)X(25)X(26) \
  X(27)X(28)X(29)X(30)X(31)

__device__ __forceinline__ int read_start(const int* start, int b) {
  // start_idx dtype hedge: int64 (LE, <2^31) => zeros at odd int32 slots.
  bool is64 = true;
  #pragma unroll 1
  for (int i = 1; i < 32; i += 2) {
    if (start[i] != 0) { is64 = false; break; }
  }
  return is64 ? start[2 * b] : start[b];
}

// ------------------------- repack: AoS -> SoA -------------------------
__global__ __launch_bounds__(256) void repack_kernel(
    const float* __restrict__ x, float* __restrict__ W)
{
  const int blk = blockIdx.x;
  const int b   = blk >> 6;         // 0..31
  const int c   = blk & 63;         // 0..63 (2048-pt chunks)
  const int t   = threadIdx.x;
  const float* xb = x + (size_t)b * BATCH_F;
  float* X = W + (size_t)b * BATCH_F;
  float* Y = X + NPTS;
  float* Z = Y + NPTS;
  #pragma unroll
  for (int i = 0; i < 8; ++i) {
    const int n = c * 2048 + i * 256 + t;
    X[n] = xb[3 * n + 0];
    Y[n] = xb[3 * n + 1];
    Z[n] = xb[3 * n + 2];
  }
}

// ------------------------- fps (SoA, float4) -------------------------
__global__ __launch_bounds__(TPB, 2) void fps_soa(
    const float* __restrict__ W, const int* __restrict__ start,
    int* __restrict__ out, unsigned long long* __restrict__ slot)
{
  #pragma clang fp contract(off)
  const int blk  = blockIdx.x;
  const int xcd  = blk & 7;           // XCD-clustered mapping
  const int j    = blk >> 3;
  const int b    = xcd * 4 + (j & 3); // 0..31
  const int part = j >> 2;            // 0..7
  const int tid  = threadIdx.x;
  const int lane = tid & 63;
  const int wave = tid >> 6;

  const float* Xb = W + (size_t)b * BATCH_F;
  const float* Yb = Xb + NPTS;
  const float* Zb = Yb + NPTS;

  int cur = read_start(start, b);
  const int S = part * PART_PTS;

  // Per-thread float4 bases: region r = wave*8 + g; lane reads 16B at l*16.
  const float4* Xt = (const float4*)(Xb + S) + wave * 512 + lane;
  const float4* Yt = (const float4*)(Yb + S) + wave * 512 + lane;
  const float4* Zt = (const float4*)(Zb + S) + wave * 512 + lane;
  const int nbase = S + wave * 2048 + lane * 4;

  #define DECLG(G) float md2_##G##_0 = __builtin_inff(),  \
      md2_##G##_1 = __builtin_inff(),                     \
      md2_##G##_2 = __builtin_inff(),                     \
      md2_##G##_3 = __builtin_inff();
  GRP8(DECLG)

  __shared__ unsigned long long wred[TPB / 64];
  __shared__ int snext;

  if (part == 0 && tid == 0) out[b * KSAMP] = cur;  // scan emits idx BEFORE update

  float cx = Xb[cur], cy = Yb[cur], cz = Zb[cur];

  unsigned long long* const srow0 = slot + (size_t)b * 2 * NPART;  // [b][2][8]

  for (int k = 0; k < KSAMP - 1; ++k) {
    float bestv = -1.0f;   // d^2 domain
    int   bestn = 0;
    #define SC(G,I,XX,YY,ZZ) {                                  \
      const float dx = (XX) - cx;                               \
      const float dy = (YY) - cy;                               \
      const float dz = (ZZ) - cz;                               \
      const float d2 = fmaf(dz, dz, fmaf(dx, dx, dy * dy));     \
      const float m  = fminf(md2_##G##_##I, d2);                \
      md2_##G##_##I = m;                                        \
      if (m > bestv) { bestv = m; bestn = nbase + (G)*256 + (I); } }
    #define SCANG(G) {                                          \
      const float4 xv = Xt[(G) * 64];                           \
      const float4 yv = Yt[(G) * 64];                           \
      const float4 zv = Zt[(G) * 64];                           \
      SC(G,0,xv.x,yv.x,zv.x)                                    \
      SC(G,1,xv.y,yv.y,zv.y)                                    \
      SC(G,2,xv.z,yv.z,zv.z)                                    \
      SC(G,3,xv.w,yv.w,zv.w) }
    GRP8(SCANG)

    const float sdw = sqrtf(bestv);   // ONE CR sqrt -> ref sd domain

    unsigned long long key =
        ((unsigned long long)__float_as_uint(sdw) << 32) |
        (unsigned int)(NPTS - 1 - bestn);

    #pragma unroll
    for (int off = 32; off >= 1; off >>= 1) {
      unsigned long long o = __shfl_xor(key, off, 64);
      if (o > key) key = o;
    }
    if (lane == 0) wred[wave] = key;
    __syncthreads();

    if (wave == 0) {
      unsigned long long v = wred[lane & 7];
      #pragma unroll
      for (int off = 4; off >= 1; off >>= 1) {
        unsigned long long o = __shfl_xor(v, off, 64);
        if (o > v) v = o;
      }

      const unsigned tag = (unsigned)(k + 1);     // 1..2047, never 0x5555 poison
      unsigned long long* const row = srow0 + (unsigned)(k & 1) * NPART;
      if (lane == 0)
        __hip_atomic_store(&row[part], v | ((unsigned long long)tag << 17),
                           __ATOMIC_RELAXED, __HIP_MEMORY_SCOPE_AGENT);

      unsigned long long g;
      do {
        g = __hip_atomic_load(&row[lane & (NPART - 1)], __ATOMIC_RELAXED,
                              __HIP_MEMORY_SCOPE_AGENT);
      } while (__ballot(((unsigned)(g >> 17) & 0x7FFFu) == tag) != ~0ull);

      #pragma unroll
      for (int off = 4; off >= 1; off >>= 1) {
        unsigned long long o = __shfl_xor(g, off, 64);
        if (o > g) g = o;
      }
      const int nidx = NPTS - 1 - (int)(g & 0x1FFFFu);
      if (lane == 0) {
        snext = nidx;
        if (part == 0) out[b * KSAMP + k + 1] = nidx;
      }
    }
    __syncthreads();

    const int nidx = snext;
    cx = Xb[nidx];
    cy = Yb[nidx];
    cz = Zb[nidx];
  }
}

// ------------------------- fallback: R10 AoS -------------------------
__global__ __launch_bounds__(TPB)
__attribute__((amdgpu_waves_per_eu(2, 2)))
void fps_aos(
    const float* __restrict__ x, const int* __restrict__ start,
    int* __restrict__ out, unsigned long long* __restrict__ slot)
{
  #pragma clang fp contract(off)
  const int blk  = blockIdx.x;
  const int xcd  = blk & 7;
  const int j    = blk >> 3;
  const int b    = xcd * 4 + (j & 3);
  const int part = j >> 2;
  const int tid  = threadIdx.x;
  const int lane = tid & 63;
  const int wave = tid >> 6;

  const float* xb = x + (size_t)b * BATCH_F;
  int cur = read_start(start, b);
  const int base = part * PART_PTS + tid;

  #define DECLP(J) float px##J, py##J, pz##J, md2##J;
  RPT32(DECLP)
  #define INITP(J) { const int n = base + (J) * TPB;          \
      px##J = xb[3*n]; py##J = xb[3*n+1]; pz##J = xb[3*n+2];  \
      md2##J = __builtin_inff(); }
  RPT32(INITP)

  __shared__ unsigned long long wred[TPB / 64];
  __shared__ int snext;

  if (part == 0 && tid == 0) out[b * KSAMP] = cur;

  float cx = xb[3 * (size_t)cur + 0];
  float cy = xb[3 * (size_t)cur + 1];
  float cz = xb[3 * (size_t)cur + 2];

  unsigned long long* const srow0 = slot + (size_t)b * 2 * NPART;

  for (int k = 0; k < KSAMP - 1; ++k) {
    float bestv = -1.0f;
    int   bestn = 0;
    #define SCANP(J) {                                              \
      const float dx = px##J - cx;                                  \
      const float dy = py##J - cy;                                  \
      const float dz = pz##J - cz;                                  \
      const float d2 = fmaf(dz, dz, fmaf(dx, dx, dy * dy));         \
      const float m  = fminf(md2##J, d2);                           \
      md2##J = m;                                                   \
      if (m > bestv) { bestv = m; bestn = base + (J) * TPB; }       \
    }
    RPT32(SCANP)

    const float sdw = sqrtf(bestv);

    unsigned long long key =
        ((unsigned long long)__float_as_uint(sdw) << 32) |
        (unsigned int)(NPTS - 1 - bestn);

    #pragma unroll
    for (int off = 32; off >= 1; off >>= 1) {
      unsigned long long o = __shfl_xor(key, off, 64);
      if (o > key) key = o;
    }
    if (lane == 0) wred[wave] = key;
    __syncthreads();

    if (wave == 0) {
      unsigned long long v = wred[lane & 7];
      #pragma unroll
      for (int off = 4; off >= 1; off >>= 1) {
        unsigned long long o = __shfl_xor(v, off, 64);
        if (o > v) v = o;
      }
      const unsigned tag = (unsigned)(k + 1);
      unsigned long long* const row = srow0 + (unsigned)(k & 1) * NPART;
      if (lane == 0)
        __hip_atomic_store(&row[part], v | ((unsigned long long)tag << 17),
                           __ATOMIC_RELAXED, __HIP_MEMORY_SCOPE_AGENT);

      unsigned long long g;
      do {
        g = __hip_atomic_load(&row[lane & (NPART - 1)], __ATOMIC_RELAXED,
                              __HIP_MEMORY_SCOPE_AGENT);
      } while (__ballot(((unsigned)(g >> 17) & 0x7FFFu) == tag) != ~0ull);

      #pragma unroll
      for (int off = 4; off >= 1; off >>= 1) {
        unsigned long long o = __shfl_xor(g, off, 64);
        if (o > g) g = o;
      }
      const int nidx = NPTS - 1 - (int)(g & 0x1FFFFu);
      if (lane == 0) {
        snext = nidx;
        if (part == 0) out[b * KSAMP + k + 1] = nidx;
      }
    }
    __syncthreads();

    const int nidx = snext;
    cx = xb[3 * (size_t)nidx + 0];
    cy = xb[3 * (size_t)nidx + 1];
    cz = xb[3 * (size_t)nidx + 2];
  }
}

extern "C" void kernel_launch(void* const* d_in, const int* in_sizes, int n_in,
                              void* d_out, int out_size, void* d_ws, size_t ws_size,
                              hipStream_t stream) {
  const float* x     = (const float*)d_in[0];
  const int*   start = (const int*)d_in[1];
  int*         out   = (int*)d_out;

  if (ws_size >= SOA_BYTES + 4096) {
    float* W = (float*)d_ws;
    unsigned long long* slot = (unsigned long long*)((char*)d_ws + SOA_BYTES);
    repack_kernel<<<dim3(NB * 64), dim3(256), 0, stream>>>(x, W);
    void* args[] = {(void*)&W, (void*)&start, (void*)&out, (void*)&slot};
    hipLaunchCooperativeKernel((void*)fps_soa, dim3(NB * NPART), dim3(TPB),
                               args, 0, stream);
  } else {
    unsigned long long* slot = (unsigned long long*)d_ws;  // 4KB
    void* args[] = {(void*)&x, (void*)&start, (void*)&out, (void*)&slot};
    hipLaunchCooperativeKernel((void*)fps_aos, dim3(NB * NPART), dim3(TPB),
                               args, 0, stream);
  }
}